// Round 4
// baseline (464.709 us; speedup 1.0000x reference)
//
#include <hip/hip_runtime.h>
#include <hip/hip_cooperative_groups.h>

namespace cg = cooperative_groups;

constexpr int N_NODES  = 50000;
constexpr int N_EDGES  = 400000;
constexpr int N_GRAPHS = 512;
constexpr int IN_DIM   = 768;
constexpr int HID      = 64;
constexpr float BN_EPS = 1e-5f;
constexpr int CAP      = 64;   // max in-degree ~27 (Poisson 8); 64 is bulletproof

typedef __attribute__((ext_vector_type(8))) short bf16x8;
typedef __attribute__((ext_vector_type(4))) float f32x4;
typedef __attribute__((ext_vector_type(2))) float f32x2;

// HW packed f32->bf16 (RNE), 1 instr per 2 elements (no builtin on gfx950)
__device__ __forceinline__ unsigned int f2bf2(float lo, float hi) {
  unsigned int r;
  asm("v_cvt_pk_bf16_f32 %0, %1, %2" : "=v"(r) : "v"(lo), "v"(hi));
  return r;
}
__device__ __forceinline__ ushort f2bf1(float f) { return (ushort)f2bf2(f, f); }

// unpack 2 bf16 (packed in a uint) -> float2
__device__ __forceinline__ f32x2 unpk(unsigned int u) {
  f32x2 v;
  v.x = __uint_as_float(u << 16);
  v.y = __uint_as_float(u & 0xffff0000u);
  return v;
}

constexpr int WB_E = HID * HID;              // 4096
constexpr int GB1  = (N_NODES + 127) / 128;  // 391 gemm tiles
constexpr int BB   = (N_EDGES + 255) / 256;  // 1563 build chunks
constexpr int GBF  = (N_NODES + 63) / 64;    // 782 mlp tiles

// LDS union: phase-1 GEMM layout (24 KB) vs phase-2/3 MLP layout (25.5 KB)
struct SMemG { ushort xs[128][64]; ushort ws[64][64]; };
struct SMemM {
  ushort xs[64][64];              // swizzled A-tile
  ushort ws[64][64];              // WT1 [col][k] swizzled
  ushort ws2[64][64];             // WT2 (CHAIN only)
  float sS[64], sT[64];           // BN scale / shift
  float gacc[64];                 // 32-graph pooling window
  float wl_s[2 * HID];            // this layer's half of wl: [64][2]
  int   sbatch[64];               // batch ids of this tile (sorted)
};
union SMem { SMemG g; SMemM m; };

struct Params {
  const float* x;
  const int*   src;
  const int*   dst;
  const int*   bat;
  const float *w1a, *w1b, *w2a, *w2b;
  const float *b1a, *g1, *be1, *rm1, *rv1, *b1b;
  const float *b2a, *g2, *be2, *rm2, *rv2, *b2b;
  const float *wl, *bl;
  ushort *P1, *P2, *WT1b, *WT2a, *WT2b;
  int    *cnt, *bucket;
  float  *out;
};

// ---- init work: cnt=0, {w1b,w2a,w2b}^T -> bf16, out = bl broadcast ----
__device__ __forceinline__ void init_work(const Params& p, int gthr, int nthr) {
  for (int i = gthr; i < N_NODES; i += nthr) p.cnt[i] = 0;
  for (int j = gthr; j < 3 * WB_E; j += nthr) {
    int w = j >> 12, r = j & (WB_E - 1);
    int c = r >> 6, k = r & 63;
    const float* W = (w == 0) ? p.w1b : (w == 1) ? p.w2a : p.w2b;
    ushort* D = (w == 0) ? p.WT1b : (w == 1) ? p.WT2a : p.WT2b;
    D[r] = f2bf1(W[k * HID + c]);
  }
  for (int o = gthr; o < N_GRAPHS * 2; o += nthr) p.out[o] = p.bl[o & 1];
}

// ---- phase-1 item A: one 128-row MFMA tile of P = bf16(X @ w1a) ----
__device__ __forceinline__ void gemm_tile(SMemG& sm, int tile,
                                          const float* __restrict__ X,
                                          const float* __restrict__ w1a,
                                          ushort* __restrict__ P, int tid) {
  const int row0 = tile * 128;
  const int wave = tid >> 6, lane = tid & 63, quad = lane >> 4, l16 = lane & 15;

  // X staging: 2 threads/row, 32 k-cols each
  const int srow = tid >> 1;
  const int sk   = (tid & 1) * 32;
  int gr = row0 + srow;
  gr = gr < N_NODES ? gr : N_NODES - 1;
  const float* xrow = &X[(size_t)gr * IN_DIM + sk];
  // W staging (self-converting): 4 threads/col, two 8-elem k-chunks each
  const int wc  = tid & 63;
  const int wj0 = (tid >> 6) * 2;

  f32x4 acc[2][4] = {};
  float4 xv[8];
  float  wf[2][8];
#pragma unroll
  for (int i = 0; i < 8; i++) xv[i] = *(const float4*)&xrow[i * 4];
#pragma unroll
  for (int jj = 0; jj < 2; jj++)
#pragma unroll
    for (int i = 0; i < 8; i++)
      wf[jj][i] = w1a[((wj0 + jj) * 8 + i) * HID + wc];

  for (int kt = 0; kt < IN_DIM; kt += 64) {
    // convert + stage current tile
    unsigned int xw[16];
#pragma unroll
    for (int i = 0; i < 8; i++) {
      xw[i * 2 + 0] = f2bf2(xv[i].x, xv[i].y);
      xw[i * 2 + 1] = f2bf2(xv[i].z, xv[i].w);
    }
#pragma unroll
    for (int j = 0; j < 4; j++)
      *(uint4*)&sm.xs[srow][(((sk >> 3) + j) ^ (srow & 7)) * 8] =
          *(const uint4*)&xw[j * 4];
#pragma unroll
    for (int jj = 0; jj < 2; jj++) {
      unsigned int pk[4];
#pragma unroll
      for (int q = 0; q < 4; q++) pk[q] = f2bf2(wf[jj][q * 2], wf[jj][q * 2 + 1]);
      *(uint4*)&sm.ws[wc][((wj0 + jj) ^ (wc & 7)) * 8] = *(const uint4*)&pk[0];
    }

    // prefetch next tile into regs (in flight across the barrier)
    if (kt + 64 < IN_DIM) {
#pragma unroll
      for (int i = 0; i < 8; i++) xv[i] = *(const float4*)&xrow[kt + 64 + i * 4];
#pragma unroll
      for (int jj = 0; jj < 2; jj++)
#pragma unroll
        for (int i = 0; i < 8; i++)
          wf[jj][i] = w1a[(kt + 64 + (wj0 + jj) * 8 + i) * HID + wc];
    }
    __syncthreads();   // tile staged

    const int ar0 = wave * 32 + l16;
    const int ar1 = ar0 + 16;
#pragma unroll
    for (int ks = 0; ks < 2; ks++) {
      bf16x8 a0 = *(const bf16x8*)&sm.xs[ar0][((ks * 4 + quad) ^ (ar0 & 7)) * 8];
      bf16x8 a1 = *(const bf16x8*)&sm.xs[ar1][((ks * 4 + quad) ^ (ar1 & 7)) * 8];
#pragma unroll
      for (int ct = 0; ct < 4; ct++) {
        const int br = ct * 16 + l16;
        bf16x8 b = *(const bf16x8*)&sm.ws[br][((ks * 4 + quad) ^ (br & 7)) * 8];
        acc[0][ct] = __builtin_amdgcn_mfma_f32_16x16x32_bf16(a0, b, acc[0][ct], 0, 0, 0);
        acc[1][ct] = __builtin_amdgcn_mfma_f32_16x16x32_bf16(a1, b, acc[1][ct], 0, 0, 0);
      }
    }
    __syncthreads();   // reads done before next stage overwrites
  }

#pragma unroll
  for (int g2 = 0; g2 < 2; g2++)
#pragma unroll
    for (int ct = 0; ct < 4; ct++)
#pragma unroll
      for (int r = 0; r < 4; r++) {
        int row = row0 + wave * 32 + g2 * 16 + quad * 4 + r;
        if (row < N_NODES)
          P[(size_t)row * HID + ct * 16 + l16] = f2bf1(acc[g2][ct][r]);
      }
}

// ---- phase-1 item B: 256 edges into dst->src buckets ----
// Bucket entries are PRE-MULTIPLIED by HID (element offsets into P).
__device__ __forceinline__ void build_chunk(int b, const Params& p, int tid) {
  int e = b * 256 + tid;
  if (e < N_EDGES) {
    int s = p.src[e];
    int d = p.dst[e];
    int slot = atomicAdd(&p.cnt[d], 1);
    if (slot < CAP) p.bucket[d * CAP + slot] = s << 6;   // s * HID
  }
}

// ---- phase 2/3: fused GIN layer over tiles t = bid, bid+stride, ... ----
template <int CHAIN>
__device__ __forceinline__ void mlp_phase(
    SMemM& sm, const int* __restrict__ cnt, const int* __restrict__ bucket,
    const ushort* __restrict__ Pin,
    const float* __restrict__ bin, const float* __restrict__ gam,
    const float* __restrict__ be, const float* __restrict__ rm,
    const float* __restrict__ rv,
    const ushort* __restrict__ WT1, const float* __restrict__ b1,
    const ushort* __restrict__ WT2, ushort* __restrict__ OUT2,
    const int* __restrict__ batch, const float* __restrict__ wlh,
    float* __restrict__ out, int tid, int bid, int stride) {
  const int srow  = tid >> 2;       // node-in-tile (staging)
  const int sub   = tid & 3;        // 16-col group
  const int qc0   = sub * 2;        // 16B-chunk pair
  const int sub16 = sub * 16;

  // stage layer invariants once per block
  if (tid < 64) {
    float s = gam[tid] * rsqrtf(rv[tid] + BN_EPS);
    sm.sS[tid] = s;
    sm.sT[tid] = (bin[tid] - rm[tid]) * s + be[tid];
  }
  if (tid < 2 * HID) sm.wl_s[tid] = wlh[tid];
  {
    uint4 w0 = *(const uint4*)&WT1[(size_t)srow * HID + qc0 * 8];
    uint4 w1 = *(const uint4*)&WT1[(size_t)srow * HID + qc0 * 8 + 8];
    *(uint4*)&sm.ws[srow][((qc0 + 0) ^ (srow & 7)) * 8] = w0;
    *(uint4*)&sm.ws[srow][((qc0 + 1) ^ (srow & 7)) * 8] = w1;
    if (CHAIN) {
      uint4 v0 = *(const uint4*)&WT2[(size_t)srow * HID + qc0 * 8];
      uint4 v1 = *(const uint4*)&WT2[(size_t)srow * HID + qc0 * 8 + 8];
      *(uint4*)&sm.ws2[srow][((qc0 + 0) ^ (srow & 7)) * 8] = v0;
      *(uint4*)&sm.ws2[srow][((qc0 + 1) ^ (srow & 7)) * 8] = v1;
    }
  }
  __syncthreads();   // sS/sT/wl_s/ws/ws2 ready

  const int wave = tid >> 6, lane = tid & 63, quad = lane >> 4, l16 = lane & 15;
  const int ar = wave * 16 + l16, axor = ar & 7;

  for (int t = bid; t < GBF; t += stride) {
    const int row0 = t * 64;

    // early issue: heads of the gather dependency chain
    int node = row0 + srow;
    node = node < N_NODES ? node : N_NODES - 1;
    const int c_raw = cnt[node];
    const int* bkt = &bucket[node * CAP];
    const int4 pre = *(const int4*)bkt;   // safe read; used only if c>=4
    unsigned int sw[8];
    {
      const ushort* sp = &Pin[node * HID + sub16];
      *(uint4*)&sw[0] = *(const uint4*)&sp[0];
      *(uint4*)&sw[4] = *(const uint4*)&sp[8];
    }
    if (tid < 64) {
      int nb = row0 + tid;
      sm.sbatch[tid] = batch[nb < N_NODES ? nb : N_NODES - 1];
      sm.gacc[tid] = 0.0f;
    }

    // gather + BN + ReLU -> stage h into xs (4 threads/node)
    {
      f32x2 acc2[8];
#pragma unroll
      for (int j = 0; j < 8; j++) acc2[j] = unpk(sw[j]);

      int c = c_raw < CAP ? c_raw : CAP;
      int i = 0;
      if (c >= 4) {
        int4 s4 = pre;
        for (; i + 4 <= c; i += 4) {
          const int4 cur = s4;
          if (i + 8 <= c) s4 = *(const int4*)&bkt[i + 4];   // prefetch
          unsigned int w0[8], w1[8], w2[8], w3[8];
          const ushort* p0 = &Pin[cur.x + sub16];   // pre-multiplied offsets
          const ushort* p1 = &Pin[cur.y + sub16];
          const ushort* p2 = &Pin[cur.z + sub16];
          const ushort* p3 = &Pin[cur.w + sub16];
          *(uint4*)&w0[0] = *(const uint4*)&p0[0]; *(uint4*)&w0[4] = *(const uint4*)&p0[8];
          *(uint4*)&w1[0] = *(const uint4*)&p1[0]; *(uint4*)&w1[4] = *(const uint4*)&p1[8];
          *(uint4*)&w2[0] = *(const uint4*)&p2[0]; *(uint4*)&w2[4] = *(const uint4*)&p2[8];
          *(uint4*)&w3[0] = *(const uint4*)&p3[0]; *(uint4*)&w3[4] = *(const uint4*)&p3[8];
#pragma unroll
          for (int j = 0; j < 8; j++)
            acc2[j] += (unpk(w0[j]) + unpk(w1[j])) + (unpk(w2[j]) + unpk(w3[j]));
        }
      }
      for (; i < c; i++) {
        const ushort* p0 = &Pin[bkt[i] + sub16];
        unsigned int w0[8];
        *(uint4*)&w0[0] = *(const uint4*)&p0[0]; *(uint4*)&w0[4] = *(const uint4*)&p0[8];
#pragma unroll
        for (int j = 0; j < 8; j++) acc2[j] += unpk(w0[j]);
      }

      unsigned int hw[8];
#pragma unroll
      for (int j = 0; j < 8; j++) {
        const int col = sub16 + j * 2;
        float x0 = fmaxf(fmaf(acc2[j].x, sm.sS[col],     sm.sT[col]),     0.0f);
        float x1 = fmaxf(fmaf(acc2[j].y, sm.sS[col + 1], sm.sT[col + 1]), 0.0f);
        hw[j] = f2bf2(x0, x1);
      }
      *(uint4*)&sm.xs[srow][((qc0 + 0) ^ (srow & 7)) * 8] = *(const uint4*)&hw[0];
      *(uint4*)&sm.xs[srow][((qc0 + 1) ^ (srow & 7)) * 8] = *(const uint4*)&hw[4];
    }
    __syncthreads();   // xs + sbatch + gacc ready

    const int g0 = sm.sbatch[0], g1v = sm.sbatch[63];
    const bool small = (g1v - g0) < 32;

    // GEMM 1: h @ W1
    f32x4 acc1[4] = {};
#pragma unroll
    for (int ks = 0; ks < 2; ks++) {
      bf16x8 a = *(const bf16x8*)&sm.xs[ar][((ks * 4 + quad) ^ axor) * 8];
#pragma unroll
      for (int ct = 0; ct < 4; ct++) {
        const int br = ct * 16 + l16;
        bf16x8 b = *(const bf16x8*)&sm.ws[br][((ks * 4 + quad) ^ (br & 7)) * 8];
        acc1[ct] = __builtin_amdgcn_mfma_f32_16x16x32_bf16(a, b, acc1[ct], 0, 0, 0);
      }
    }

    if (CHAIN) __syncthreads();   // all xs reads done before restage overwrite

    // epilogue: xL = relu(acc1 + b1) (C layout: col=ct*16+l16, row=quad*4+r)
    float v[4][4];
#pragma unroll
    for (int ct = 0; ct < 4; ct++) {
      const float bo = b1[ct * 16 + l16];
#pragma unroll
      for (int r = 0; r < 4; r++) v[ct][r] = fmaxf(acc1[ct][r] + bo, 0.0f);
    }

    // fused pool partial: p[r] = xL[row] . wlh
    {
      float p0[4] = {}, p1[4] = {};
#pragma unroll
      for (int ct = 0; ct < 4; ct++) {
        const int col = ct * 16 + l16;
        const float w0 = sm.wl_s[col * 2 + 0], w1 = sm.wl_s[col * 2 + 1];
#pragma unroll
        for (int r = 0; r < 4; r++) {
          p0[r] = fmaf(v[ct][r], w0, p0[r]);
          p1[r] = fmaf(v[ct][r], w1, p1[r]);
        }
      }
#pragma unroll
      for (int m = 1; m < 16; m <<= 1) {
#pragma unroll
        for (int r = 0; r < 4; r++) {
          p0[r] += __shfl_xor(p0[r], m);
          p1[r] += __shfl_xor(p1[r], m);
        }
      }
      if (l16 == 0) {
#pragma unroll
        for (int r = 0; r < 4; r++) {
          int lrow = wave * 16 + quad * 4 + r;
          if (row0 + lrow < N_NODES) {
            int gi = sm.sbatch[lrow];
            if (small) {
              atomicAdd(&sm.gacc[(gi - g0) * 2 + 0], p0[r]);
              atomicAdd(&sm.gacc[(gi - g0) * 2 + 1], p1[r]);
            } else {
              atomicAdd(&out[gi * 2 + 0], p0[r]);
              atomicAdd(&out[gi * 2 + 1], p1[r]);
            }
          }
        }
      }
    }

    if (CHAIN) {
      // restage bf16(xL) into xs, then GEMM 2: xL @ W2 -> OUT2
#pragma unroll
      for (int ct = 0; ct < 4; ct++) {
        const int col = ct * 16 + l16;
#pragma unroll
        for (int r = 0; r < 4; r++) {
          int lrow = wave * 16 + quad * 4 + r;
          sm.xs[lrow][(((col >> 3) ^ (lrow & 7)) * 8) + (col & 7)] = f2bf1(v[ct][r]);
        }
      }
      __syncthreads();

      f32x4 accB[4] = {};
#pragma unroll
      for (int ks = 0; ks < 2; ks++) {
        bf16x8 a = *(const bf16x8*)&sm.xs[ar][((ks * 4 + quad) ^ axor) * 8];
#pragma unroll
        for (int ct = 0; ct < 4; ct++) {
          const int br = ct * 16 + l16;
          bf16x8 b = *(const bf16x8*)&sm.ws2[br][((ks * 4 + quad) ^ (br & 7)) * 8];
          accB[ct] = __builtin_amdgcn_mfma_f32_16x16x32_bf16(a, b, accB[ct], 0, 0, 0);
        }
      }
#pragma unroll
      for (int ct = 0; ct < 4; ct++) {
        const int col = ct * 16 + l16;
#pragma unroll
        for (int r = 0; r < 4; r++) {
          int grow = row0 + wave * 16 + quad * 4 + r;
          if (grow < N_NODES) OUT2[(size_t)grow * HID + col] = f2bf1(accB[ct][r]);
        }
      }
    }

    // flush per-block graph partials (tiny window: batch is sorted)
    __syncthreads();
    if (small) {
      const int span2 = (g1v - g0 + 1) * 2;
      for (int z = tid; z < span2; z += 256) {
        float vv = sm.gacc[z];
        if (vv != 0.0f) atomicAdd(&out[g0 * 2 + z], vv);
      }
    }
    __syncthreads();   // protect gacc/sbatch/xs for next tile
  }
}

// ---- the whole pipeline as ONE cooperative kernel, 4 phases / 3 grid syncs ----
// launch_bounds(256, 2): cap VGPR at 256 so >=2 blocks/CU are co-residentable;
// the host sizes the grid from the occupancy query.
__global__ __launch_bounds__(256, 2) void mega(Params p) {
  __shared__ SMem sm;
  cg::grid_group grid = cg::this_grid();
  const int tid  = threadIdx.x;
  const int bid  = blockIdx.x;
  const int nb   = gridDim.x;
  const int nthr = nb * 256;

  // ---- phase 0: init ----
  init_work(p, bid * 256 + tid, nthr);
  grid.sync();

  // ---- phase 1: GEMM tiles (items [0,GB1)) + bucket build ([GB1,GB1+BB)) ----
  for (int item = bid; item < GB1 + BB; item += nb) {
    if (item < GB1) gemm_tile(sm.g, item, p.x, p.w1a, p.P1, tid);
    else            build_chunk(item - GB1, p, tid);
  }
  grid.sync();

  // ---- phase 2: layer 1 (+ chain P2 = x1 @ w2a) ----
  mlp_phase<1>(sm.m, p.cnt, p.bucket, p.P1, p.b1a, p.g1, p.be1, p.rm1, p.rv1,
               p.WT1b, p.b1b, p.WT2a, p.P2, p.bat, p.wl, p.out, tid, bid, nb);
  grid.sync();

  // ---- phase 3: layer 2 ----
  mlp_phase<0>(sm.m, p.cnt, p.bucket, p.P2, p.b2a, p.g2, p.be2, p.rm2, p.rv2,
               p.WT2b, p.b2b, nullptr, nullptr, p.bat, p.wl + 2 * HID, p.out,
               tid, bid, nb);
}

// ---- fallback multi-kernel pipeline (round-2-verified structure) ----
__global__ __launch_bounds__(256) void init_k(Params p) {
  init_work(p, blockIdx.x * 256 + threadIdx.x, gridDim.x * 256);
}
__global__ __launch_bounds__(256) void gb_k(Params p) {
  __shared__ SMemG smg;
  if (blockIdx.x < GB1) gemm_tile(smg, blockIdx.x, p.x, p.w1a, p.P1, threadIdx.x);
  else                  build_chunk(blockIdx.x - GB1, p, threadIdx.x);
}
template <int CHAIN>
__global__ __launch_bounds__(256) void mlp_k(Params p) {
  __shared__ SMemM smm;
  if (CHAIN)
    mlp_phase<1>(smm, p.cnt, p.bucket, p.P1, p.b1a, p.g1, p.be1, p.rm1, p.rv1,
                 p.WT1b, p.b1b, p.WT2a, p.P2, p.bat, p.wl, p.out,
                 threadIdx.x, blockIdx.x, gridDim.x);
  else
    mlp_phase<0>(smm, p.cnt, p.bucket, p.P2, p.b2a, p.g2, p.be2, p.rm2, p.rv2,
                 p.WT2b, p.b2b, nullptr, nullptr, p.bat, p.wl + 2 * HID, p.out,
                 threadIdx.x, blockIdx.x, gridDim.x);
}

extern "C" void kernel_launch(void* const* d_in, const int* in_sizes, int n_in,
                              void* d_out, int out_size, void* d_ws, size_t ws_size,
                              hipStream_t stream) {
  Params p;
  p.x   = (const float*)d_in[0];
  const int* ei = (const int*)d_in[1];
  p.src = ei;
  p.dst = ei + N_EDGES;
  p.bat = (const int*)d_in[2];
  p.w1a = (const float*)d_in[3];
  p.b1a = (const float*)d_in[4];
  p.g1  = (const float*)d_in[5];
  p.be1 = (const float*)d_in[6];
  p.rm1 = (const float*)d_in[7];
  p.rv1 = (const float*)d_in[8];
  p.w1b = (const float*)d_in[9];
  p.b1b = (const float*)d_in[10];
  p.w2a = (const float*)d_in[11];
  p.b2a = (const float*)d_in[12];
  p.g2  = (const float*)d_in[13];
  p.be2 = (const float*)d_in[14];
  p.rm2 = (const float*)d_in[15];
  p.rv2 = (const float*)d_in[16];
  p.w2b = (const float*)d_in[17];
  p.b2b = (const float*)d_in[18];
  p.wl  = (const float*)d_in[19];
  p.bl  = (const float*)d_in[20];
  p.out = (float*)d_out;

  const size_t FB = (size_t)N_NODES * HID;
  p.P1     = (ushort*)d_ws;                  // 6.4 MB
  p.P2     = p.P1 + FB;                      // 6.4 MB
  p.WT1b   = p.P2 + FB;                      // 8 KB each
  p.WT2a   = p.WT1b + WB_E;
  p.WT2b   = p.WT2a + WB_E;
  p.cnt    = (int*)(p.WT2b + WB_E);          // 200 KB
  p.bucket = p.cnt + N_NODES;                // 12.8 MB  (total ~26 MB)

  // co-residency capacity for the cooperative launch (host-side query, cached)
  static int coop_grid = -1;
  if (coop_grid < 0) {
    int maxb = 0;
    hipDeviceProp_t prop{};
    if (hipOccupancyMaxActiveBlocksPerMultiprocessor(
            &maxb, (const void*)mega, 256, 0) == hipSuccess &&
        hipGetDeviceProperties(&prop, 0) == hipSuccess && maxb > 0)
      coop_grid = maxb * prop.multiProcessorCount;
    else
      coop_grid = 0;
  }

  if (coop_grid > 0) {
    int nblk = coop_grid < 2048 ? coop_grid : 2048;
    void* kargs[] = { (void*)&p };
    if (hipLaunchCooperativeKernel((const void*)mega, dim3(nblk), dim3(256),
                                   kargs, 0, stream) == hipSuccess)
      return;
    coop_grid = 0;   // never retry the coop path
  }

  // ---- fallback: verified 4-launch pipeline ----
  init_k<<<(N_NODES + 255) / 256, 256, 0, stream>>>(p);
  gb_k<<<GB1 + BB, 256, 0, stream>>>(p);
  mlp_k<1><<<GBF, 256, 0, stream>>>(p);
  mlp_k<0><<<GBF, 256, 0, stream>>>(p);
}

// Round 5
// 319.283 us; speedup vs baseline: 1.4555x; 1.4555x over previous
//
#include <hip/hip_runtime.h>

constexpr int N_NODES  = 50000;
constexpr int N_EDGES  = 400000;
constexpr int N_GRAPHS = 512;
constexpr int IN_DIM   = 768;
constexpr int HID      = 64;
constexpr float BN_EPS = 1e-5f;
constexpr int CAP      = 64;   // max in-degree ~27 (Poisson 8); 64 is bulletproof

typedef __attribute__((ext_vector_type(8))) short bf16x8;
typedef __attribute__((ext_vector_type(4))) float f32x4;
typedef __attribute__((ext_vector_type(2))) float f32x2;

// HW packed f32->bf16 (RNE), 1 instr per 2 elements (no builtin on gfx950)
__device__ __forceinline__ unsigned int f2bf2(float lo, float hi) {
  unsigned int r;
  asm("v_cvt_pk_bf16_f32 %0, %1, %2" : "=v"(r) : "v"(lo), "v"(hi));
  return r;
}
__device__ __forceinline__ ushort f2bf1(float f) { return (ushort)f2bf2(f, f); }

// unpack 2 bf16 (packed in a uint) -> float2
__device__ __forceinline__ f32x2 unpk(unsigned int u) {
  f32x2 v;
  v.x = __uint_as_float(u << 16);
  v.y = __uint_as_float(u & 0xffff0000u);
  return v;
}

constexpr int WB_E = HID * HID;              // 4096
constexpr int GB64 = (N_NODES + 63) / 64;    // 782 gemm tiles (64-row)
constexpr int BB   = (N_EDGES + 255) / 256;  // 1563 build chunks
constexpr int GBF  = (N_NODES + 63) / 64;    // 782 mlp tiles

struct SMemG { ushort xs[64][64]; ushort ws[64][64]; };   // 16 KB
struct SMemM {
  ushort xs[64][64];              // swizzled A-tile
  ushort ws[64][64];              // WT1 [col][k] swizzled
  ushort ws2[64][64];             // WT2 (CHAIN only)
  float sS[64], sT[64];           // BN scale / shift
  float gacc[64];                 // 32-graph pooling window
  float wl_s[2 * HID];            // this layer's half of wl: [64][2]
  int   sbatch[64];               // batch ids of this tile (sorted)
};

struct Params {
  const float* x;
  const int*   src;
  const int*   dst;
  const int*   bat;
  const float *w1a, *w1b, *w2a, *w2b;
  const float *b1a, *g1, *be1, *rm1, *rv1, *b1b;
  const float *b2a, *g2, *be2, *rm2, *rv2, *b2b;
  const float *wl, *bl;
  ushort *P1, *P2, *WT1b, *WT2a, *WT2b;
  int    *cnt, *bucket;
  float  *out;
};

// ---- init work: cnt=0, {w1b,w2a,w2b}^T -> bf16, out = bl broadcast ----
__device__ __forceinline__ void init_work(const Params& p, int gthr, int nthr) {
  for (int i = gthr; i < N_NODES; i += nthr) p.cnt[i] = 0;
  for (int j = gthr; j < 3 * WB_E; j += nthr) {
    int w = j >> 12, r = j & (WB_E - 1);
    int c = r >> 6, k = r & 63;
    const float* W = (w == 0) ? p.w1b : (w == 1) ? p.w2a : p.w2b;
    ushort* D = (w == 0) ? p.WT1b : (w == 1) ? p.WT2a : p.WT2b;
    D[r] = f2bf1(W[k * HID + c]);
  }
  for (int o = gthr; o < N_GRAPHS * 2; o += nthr) p.out[o] = p.bl[o & 1];
}

// ---- one 64-row MFMA tile of P = bf16(X @ w1a) ----
// 256 threads / 4 waves; wave owns 16 rows (same layout as mlp GEMM1).
// X staged 4 threads/row x 16 cols; w1a self-converted from fp32.
__device__ __forceinline__ void gemm_tile(SMemG& sm, int tile,
                                          const float* __restrict__ X,
                                          const float* __restrict__ w1a,
                                          ushort* __restrict__ P, int tid) {
  const int row0 = tile * 64;
  const int wave = tid >> 6, lane = tid & 63, quad = lane >> 4, l16 = lane & 15;

  // X staging: 4 threads/row, 16 k-cols each
  const int srow = tid >> 2;
  const int sk   = (tid & 3) * 16;
  const int qc0  = (tid & 3) * 2;     // 16B-chunk pair within the row
  int gr = row0 + srow;
  gr = gr < N_NODES ? gr : N_NODES - 1;
  const float* xrow = &X[(size_t)gr * IN_DIM + sk];
  // W staging (self-converting): 4 threads/col, two 8-elem k-chunks each
  const int wc  = tid & 63;
  const int wj0 = (tid >> 6) * 2;

  f32x4 acc[4] = {};
  float4 xv[4];
  float  wf[2][8];
#pragma unroll
  for (int i = 0; i < 4; i++) xv[i] = *(const float4*)&xrow[i * 4];
#pragma unroll
  for (int jj = 0; jj < 2; jj++)
#pragma unroll
    for (int i = 0; i < 8; i++)
      wf[jj][i] = w1a[((wj0 + jj) * 8 + i) * HID + wc];

  for (int kt = 0; kt < IN_DIM; kt += 64) {
    // convert + stage current tile
    unsigned int xw[8];
#pragma unroll
    for (int i = 0; i < 4; i++) {
      xw[i * 2 + 0] = f2bf2(xv[i].x, xv[i].y);
      xw[i * 2 + 1] = f2bf2(xv[i].z, xv[i].w);
    }
#pragma unroll
    for (int j = 0; j < 2; j++)
      *(uint4*)&sm.xs[srow][((qc0 + j) ^ (srow & 7)) * 8] =
          *(const uint4*)&xw[j * 4];
#pragma unroll
    for (int jj = 0; jj < 2; jj++) {
      unsigned int pk[4];
#pragma unroll
      for (int q = 0; q < 4; q++) pk[q] = f2bf2(wf[jj][q * 2], wf[jj][q * 2 + 1]);
      *(uint4*)&sm.ws[wc][((wj0 + jj) ^ (wc & 7)) * 8] = *(const uint4*)&pk[0];
    }

    // prefetch next k-tile into regs (in flight across the barrier)
    if (kt + 64 < IN_DIM) {
#pragma unroll
      for (int i = 0; i < 4; i++) xv[i] = *(const float4*)&xrow[kt + 64 + i * 4];
#pragma unroll
      for (int jj = 0; jj < 2; jj++)
#pragma unroll
        for (int i = 0; i < 8; i++)
          wf[jj][i] = w1a[(kt + 64 + (wj0 + jj) * 8 + i) * HID + wc];
    }
    __syncthreads();   // tile staged

    const int ar = wave * 16 + l16, axor = ar & 7;
#pragma unroll
    for (int ks = 0; ks < 2; ks++) {
      bf16x8 a = *(const bf16x8*)&sm.xs[ar][((ks * 4 + quad) ^ axor) * 8];
#pragma unroll
      for (int ct = 0; ct < 4; ct++) {
        const int br = ct * 16 + l16;
        bf16x8 b = *(const bf16x8*)&sm.ws[br][((ks * 4 + quad) ^ (br & 7)) * 8];
        acc[ct] = __builtin_amdgcn_mfma_f32_16x16x32_bf16(a, b, acc[ct], 0, 0, 0);
      }
    }
    __syncthreads();   // reads done before next stage overwrites
  }

#pragma unroll
  for (int ct = 0; ct < 4; ct++)
#pragma unroll
    for (int r = 0; r < 4; r++) {
      int row = row0 + wave * 16 + quad * 4 + r;
      if (row < N_NODES)
        P[(size_t)row * HID + ct * 16 + l16] = f2bf1(acc[ct][r]);
    }
}

// ---- 256 edges into dst->src buckets ----
// Bucket entries are PRE-MULTIPLIED by HID (element offsets into P).
__device__ __forceinline__ void build_chunk(int b, const Params& p, int tid) {
  int e = b * 256 + tid;
  if (e < N_EDGES) {
    int s = p.src[e];
    int d = p.dst[e];
    int slot = atomicAdd(&p.cnt[d], 1);
    if (slot < CAP) p.bucket[d * CAP + slot] = s << 6;   // s * HID
  }
}

// ---- fused GIN layer over tiles t = bid, bid+stride, ... ----
template <int CHAIN>
__device__ __forceinline__ void mlp_phase(
    SMemM& sm, const int* __restrict__ cnt, const int* __restrict__ bucket,
    const ushort* __restrict__ Pin,
    const float* __restrict__ bin, const float* __restrict__ gam,
    const float* __restrict__ be, const float* __restrict__ rm,
    const float* __restrict__ rv,
    const ushort* __restrict__ WT1, const float* __restrict__ b1,
    const ushort* __restrict__ WT2, ushort* __restrict__ OUT2,
    const int* __restrict__ batch, const float* __restrict__ wlh,
    float* __restrict__ out, int tid, int bid, int stride) {
  const int srow  = tid >> 2;       // node-in-tile (staging)
  const int sub   = tid & 3;        // 16-col group
  const int qc0   = sub * 2;        // 16B-chunk pair
  const int sub16 = sub * 16;

  // stage layer invariants once per block
  if (tid < 64) {
    float s = gam[tid] * rsqrtf(rv[tid] + BN_EPS);
    sm.sS[tid] = s;
    sm.sT[tid] = (bin[tid] - rm[tid]) * s + be[tid];
  }
  if (tid < 2 * HID) sm.wl_s[tid] = wlh[tid];
  {
    uint4 w0 = *(const uint4*)&WT1[(size_t)srow * HID + qc0 * 8];
    uint4 w1 = *(const uint4*)&WT1[(size_t)srow * HID + qc0 * 8 + 8];
    *(uint4*)&sm.ws[srow][((qc0 + 0) ^ (srow & 7)) * 8] = w0;
    *(uint4*)&sm.ws[srow][((qc0 + 1) ^ (srow & 7)) * 8] = w1;
    if (CHAIN) {
      uint4 v0 = *(const uint4*)&WT2[(size_t)srow * HID + qc0 * 8];
      uint4 v1 = *(const uint4*)&WT2[(size_t)srow * HID + qc0 * 8 + 8];
      *(uint4*)&sm.ws2[srow][((qc0 + 0) ^ (srow & 7)) * 8] = v0;
      *(uint4*)&sm.ws2[srow][((qc0 + 1) ^ (srow & 7)) * 8] = v1;
    }
  }
  __syncthreads();   // sS/sT/wl_s/ws/ws2 ready

  const int wave = tid >> 6, lane = tid & 63, quad = lane >> 4, l16 = lane & 15;
  const int ar = wave * 16 + l16, axor = ar & 7;

  for (int t = bid; t < GBF; t += stride) {
    const int row0 = t * 64;

    // early issue: heads of the gather dependency chain
    int node = row0 + srow;
    node = node < N_NODES ? node : N_NODES - 1;
    const int c_raw = cnt[node];
    const int* bkt = &bucket[node * CAP];
    const int4 pre = *(const int4*)bkt;   // safe read; used only if c>=4
    unsigned int sw[8];
    {
      const ushort* sp = &Pin[node * HID + sub16];
      *(uint4*)&sw[0] = *(const uint4*)&sp[0];
      *(uint4*)&sw[4] = *(const uint4*)&sp[8];
    }
    if (tid < 64) {
      int nb = row0 + tid;
      sm.sbatch[tid] = batch[nb < N_NODES ? nb : N_NODES - 1];
      sm.gacc[tid] = 0.0f;
    }

    // gather + BN + ReLU -> stage h into xs (4 threads/node)
    {
      f32x2 acc2[8];
#pragma unroll
      for (int j = 0; j < 8; j++) acc2[j] = unpk(sw[j]);

      int c = c_raw < CAP ? c_raw : CAP;
      int i = 0;
      if (c >= 4) {
        int4 s4 = pre;
        for (; i + 4 <= c; i += 4) {
          const int4 cur = s4;
          if (i + 8 <= c) s4 = *(const int4*)&bkt[i + 4];   // prefetch
          unsigned int w0[8], w1[8], w2[8], w3[8];
          const ushort* p0 = &Pin[cur.x + sub16];   // pre-multiplied offsets
          const ushort* p1 = &Pin[cur.y + sub16];
          const ushort* p2 = &Pin[cur.z + sub16];
          const ushort* p3 = &Pin[cur.w + sub16];
          *(uint4*)&w0[0] = *(const uint4*)&p0[0]; *(uint4*)&w0[4] = *(const uint4*)&p0[8];
          *(uint4*)&w1[0] = *(const uint4*)&p1[0]; *(uint4*)&w1[4] = *(const uint4*)&p1[8];
          *(uint4*)&w2[0] = *(const uint4*)&p2[0]; *(uint4*)&w2[4] = *(const uint4*)&p2[8];
          *(uint4*)&w3[0] = *(const uint4*)&p3[0]; *(uint4*)&w3[4] = *(const uint4*)&p3[8];
#pragma unroll
          for (int j = 0; j < 8; j++)
            acc2[j] += (unpk(w0[j]) + unpk(w1[j])) + (unpk(w2[j]) + unpk(w3[j]));
        }
      }
      for (; i < c; i++) {
        const ushort* p0 = &Pin[bkt[i] + sub16];
        unsigned int w0[8];
        *(uint4*)&w0[0] = *(const uint4*)&p0[0]; *(uint4*)&w0[4] = *(const uint4*)&p0[8];
#pragma unroll
        for (int j = 0; j < 8; j++) acc2[j] += unpk(w0[j]);
      }

      unsigned int hw[8];
#pragma unroll
      for (int j = 0; j < 8; j++) {
        const int col = sub16 + j * 2;
        float x0 = fmaxf(fmaf(acc2[j].x, sm.sS[col],     sm.sT[col]),     0.0f);
        float x1 = fmaxf(fmaf(acc2[j].y, sm.sS[col + 1], sm.sT[col + 1]), 0.0f);
        hw[j] = f2bf2(x0, x1);
      }
      *(uint4*)&sm.xs[srow][((qc0 + 0) ^ (srow & 7)) * 8] = *(const uint4*)&hw[0];
      *(uint4*)&sm.xs[srow][((qc0 + 1) ^ (srow & 7)) * 8] = *(const uint4*)&hw[4];
    }
    __syncthreads();   // xs + sbatch + gacc ready

    const int g0 = sm.sbatch[0], g1v = sm.sbatch[63];
    const bool small = (g1v - g0) < 32;

    // GEMM 1: h @ W1
    f32x4 acc1[4] = {};
#pragma unroll
    for (int ks = 0; ks < 2; ks++) {
      bf16x8 a = *(const bf16x8*)&sm.xs[ar][((ks * 4 + quad) ^ axor) * 8];
#pragma unroll
      for (int ct = 0; ct < 4; ct++) {
        const int br = ct * 16 + l16;
        bf16x8 b = *(const bf16x8*)&sm.ws[br][((ks * 4 + quad) ^ (br & 7)) * 8];
        acc1[ct] = __builtin_amdgcn_mfma_f32_16x16x32_bf16(a, b, acc1[ct], 0, 0, 0);
      }
    }

    if (CHAIN) __syncthreads();   // all xs reads done before restage overwrite

    // epilogue: xL = relu(acc1 + b1) (C layout: col=ct*16+l16, row=quad*4+r)
    float v[4][4];
#pragma unroll
    for (int ct = 0; ct < 4; ct++) {
      const float bo = b1[ct * 16 + l16];
#pragma unroll
      for (int r = 0; r < 4; r++) v[ct][r] = fmaxf(acc1[ct][r] + bo, 0.0f);
    }

    // fused pool partial: p[r] = xL[row] . wlh
    {
      float p0[4] = {}, p1[4] = {};
#pragma unroll
      for (int ct = 0; ct < 4; ct++) {
        const int col = ct * 16 + l16;
        const float w0 = sm.wl_s[col * 2 + 0], w1 = sm.wl_s[col * 2 + 1];
#pragma unroll
        for (int r = 0; r < 4; r++) {
          p0[r] = fmaf(v[ct][r], w0, p0[r]);
          p1[r] = fmaf(v[ct][r], w1, p1[r]);
        }
      }
#pragma unroll
      for (int m = 1; m < 16; m <<= 1) {
#pragma unroll
        for (int r = 0; r < 4; r++) {
          p0[r] += __shfl_xor(p0[r], m);
          p1[r] += __shfl_xor(p1[r], m);
        }
      }
      if (l16 == 0) {
#pragma unroll
        for (int r = 0; r < 4; r++) {
          int lrow = wave * 16 + quad * 4 + r;
          if (row0 + lrow < N_NODES) {
            int gi = sm.sbatch[lrow];
            if (small) {
              atomicAdd(&sm.gacc[(gi - g0) * 2 + 0], p0[r]);
              atomicAdd(&sm.gacc[(gi - g0) * 2 + 1], p1[r]);
            } else {
              atomicAdd(&out[gi * 2 + 0], p0[r]);
              atomicAdd(&out[gi * 2 + 1], p1[r]);
            }
          }
        }
      }
    }

    if (CHAIN) {
      // restage bf16(xL) into xs, then GEMM 2: xL @ W2 -> OUT2
#pragma unroll
      for (int ct = 0; ct < 4; ct++) {
        const int col = ct * 16 + l16;
#pragma unroll
        for (int r = 0; r < 4; r++) {
          int lrow = wave * 16 + quad * 4 + r;
          sm.xs[lrow][(((col >> 3) ^ (lrow & 7)) * 8) + (col & 7)] = f2bf1(v[ct][r]);
        }
      }
      __syncthreads();

      f32x4 accB[4] = {};
#pragma unroll
      for (int ks = 0; ks < 2; ks++) {
        bf16x8 a = *(const bf16x8*)&sm.xs[ar][((ks * 4 + quad) ^ axor) * 8];
#pragma unroll
        for (int ct = 0; ct < 4; ct++) {
          const int br = ct * 16 + l16;
          bf16x8 b = *(const bf16x8*)&sm.ws2[br][((ks * 4 + quad) ^ (br & 7)) * 8];
          accB[ct] = __builtin_amdgcn_mfma_f32_16x16x32_bf16(a, b, accB[ct], 0, 0, 0);
        }
      }
#pragma unroll
      for (int ct = 0; ct < 4; ct++) {
        const int col = ct * 16 + l16;
#pragma unroll
        for (int r = 0; r < 4; r++) {
          int grow = row0 + wave * 16 + quad * 4 + r;
          if (grow < N_NODES) OUT2[(size_t)grow * HID + col] = f2bf1(accB[ct][r]);
        }
      }
    }

    // flush per-block graph partials (tiny window: batch is sorted)
    __syncthreads();
    if (small) {
      const int span2 = (g1v - g0 + 1) * 2;
      for (int z = tid; z < span2; z += 256) {
        float vv = sm.gacc[z];
        if (vv != 0.0f) atomicAdd(&out[g0 * 2 + z], vv);
      }
    }
    __syncthreads();   // protect gacc/sbatch/xs for next tile
  }
}

// ---- kernels ----
__global__ __launch_bounds__(256) void init_k(Params p) {
  init_work(p, blockIdx.x * 256 + threadIdx.x, gridDim.x * 256);
}
// Hybrid: blocks [0,GB64) = 64-row GEMM tiles; [GB64, GB64+BB) = bucket build.
__global__ __launch_bounds__(256) void gb_k(Params p) {
  __shared__ SMemG smg;
  if (blockIdx.x < GB64) gemm_tile(smg, blockIdx.x, p.x, p.w1a, p.P1, threadIdx.x);
  else                   build_chunk(blockIdx.x - GB64, p, threadIdx.x);
}
template <int CHAIN>
__global__ __launch_bounds__(256) void mlp_k(Params p) {
  __shared__ SMemM smm;
  if (CHAIN)
    mlp_phase<1>(smm, p.cnt, p.bucket, p.P1, p.b1a, p.g1, p.be1, p.rm1, p.rv1,
                 p.WT1b, p.b1b, p.WT2a, p.P2, p.bat, p.wl, p.out,
                 threadIdx.x, blockIdx.x, gridDim.x);
  else
    mlp_phase<0>(smm, p.cnt, p.bucket, p.P2, p.b2a, p.g2, p.be2, p.rm2, p.rv2,
                 p.WT2b, p.b2b, nullptr, nullptr, p.bat, p.wl + 2 * HID, p.out,
                 threadIdx.x, blockIdx.x, gridDim.x);
}

extern "C" void kernel_launch(void* const* d_in, const int* in_sizes, int n_in,
                              void* d_out, int out_size, void* d_ws, size_t ws_size,
                              hipStream_t stream) {
  Params p;
  p.x   = (const float*)d_in[0];
  const int* ei = (const int*)d_in[1];
  p.src = ei;
  p.dst = ei + N_EDGES;
  p.bat = (const int*)d_in[2];
  p.w1a = (const float*)d_in[3];
  p.b1a = (const float*)d_in[4];
  p.g1  = (const float*)d_in[5];
  p.be1 = (const float*)d_in[6];
  p.rm1 = (const float*)d_in[7];
  p.rv1 = (const float*)d_in[8];
  p.w1b = (const float*)d_in[9];
  p.b1b = (const float*)d_in[10];
  p.w2a = (const float*)d_in[11];
  p.b2a = (const float*)d_in[12];
  p.g2  = (const float*)d_in[13];
  p.be2 = (const float*)d_in[14];
  p.rm2 = (const float*)d_in[15];
  p.rv2 = (const float*)d_in[16];
  p.w2b = (const float*)d_in[17];
  p.b2b = (const float*)d_in[18];
  p.wl  = (const float*)d_in[19];
  p.bl  = (const float*)d_in[20];
  p.out = (float*)d_out;

  const size_t FB = (size_t)N_NODES * HID;
  p.P1     = (ushort*)d_ws;                  // 6.4 MB
  p.P2     = p.P1 + FB;                      // 6.4 MB
  p.WT1b   = p.P2 + FB;                      // 8 KB each
  p.WT2a   = p.WT1b + WB_E;
  p.WT2b   = p.WT2a + WB_E;
  p.cnt    = (int*)(p.WT2b + WB_E);          // 200 KB
  p.bucket = p.cnt + N_NODES;                // 12.8 MB  (total ~26 MB)

  init_k<<<(N_NODES + 255) / 256, 256, 0, stream>>>(p);
  gb_k<<<GB64 + BB, 256, 0, stream>>>(p);
  mlp_k<1><<<GBF, 256, 0, stream>>>(p);
  mlp_k<0><<<GBF, 256, 0, stream>>>(p);
}

// Round 6
// 304.075 us; speedup vs baseline: 1.5283x; 1.0500x over previous
//
#include <hip/hip_runtime.h>

constexpr int N_NODES  = 50000;
constexpr int N_EDGES  = 400000;
constexpr int N_GRAPHS = 512;
constexpr int IN_DIM   = 768;
constexpr int HID      = 64;
constexpr float BN_EPS = 1e-5f;
constexpr int CAP      = 64;   // max in-degree ~27 (Poisson 8); 64 is bulletproof

typedef __attribute__((ext_vector_type(8))) short bf16x8;
typedef __attribute__((ext_vector_type(4))) float f32x4;
typedef __attribute__((ext_vector_type(2))) float f32x2;

// HW packed f32->bf16 (RNE), 1 instr per 2 elements (no builtin on gfx950)
__device__ __forceinline__ unsigned int f2bf2(float lo, float hi) {
  unsigned int r;
  asm("v_cvt_pk_bf16_f32 %0, %1, %2" : "=v"(r) : "v"(lo), "v"(hi));
  return r;
}
__device__ __forceinline__ ushort f2bf1(float f) { return (ushort)f2bf2(f, f); }

// unpack 2 bf16 (packed in a uint) -> float2
__device__ __forceinline__ f32x2 unpk(unsigned int u) {
  f32x2 v;
  v.x = __uint_as_float(u << 16);
  v.y = __uint_as_float(u & 0xffff0000u);
  return v;
}

// w1a^T -> WT, {w1b,w2a,w2b}^T -> WT*b (bf16), out = bl bcast, cnt = 0
constexpr int W1A_E = HID * IN_DIM;     // 49152
constexpr int WB_E  = HID * HID;        // 4096
__global__ __launch_bounds__(256) void convert_all(
    const float* __restrict__ w1a, const float* __restrict__ w1b,
    const float* __restrict__ w2a, const float* __restrict__ w2b,
    const float* __restrict__ bl,
    ushort* __restrict__ WT, ushort* __restrict__ WT1b,
    ushort* __restrict__ WT2a, ushort* __restrict__ WT2b,
    float* __restrict__ out, int* __restrict__ cnt) {
  int i = blockIdx.x * 256 + threadIdx.x;
  if (i < W1A_E) {
    int c = i / IN_DIM, k = i - c * IN_DIM;
    WT[i] = f2bf1(w1a[(size_t)k * HID + c]);
    return;
  }
  int j = i - W1A_E;
  if (j < 3 * WB_E) {
    int w = j / WB_E, r = j - w * WB_E;
    int c = r / HID, k = r - c * HID;
    const float* W = (w == 0) ? w1b : (w == 1) ? w2a : w2b;
    ushort* D = (w == 0) ? WT1b : (w == 1) ? WT2a : WT2b;
    D[r] = f2bf1(W[(size_t)k * HID + c]);
    return;
  }
  int o = j - 3 * WB_E;
  if (o < N_GRAPHS * 2) { out[o] = bl[o & 1]; return; }
  int z = o - N_GRAPHS * 2;
  if (z < N_NODES) cnt[z] = 0;
}

constexpr int GB1 = (N_NODES + 127) / 128;   // 391 gemm blocks
constexpr int BB  = (N_EDGES + 255) / 256;   // 1563 build blocks
constexpr int GBF = (N_NODES + 63) / 64;     // 782 mlp tiles

// Hybrid dispatch: blocks [0,GB1) compute P[n,64] = bf16(X @ w1a) via MFMA
// (128-row tiles); blocks [GB1, GB1+BB) build the dst->src buckets.
// Bucket entries are PRE-MULTIPLIED by HID (element offsets into P).
__global__ __launch_bounds__(256) void gemm_build(const float* __restrict__ X,
                                                  const ushort* __restrict__ WT,
                                                  ushort* __restrict__ P,
                                                  const int* __restrict__ src,
                                                  const int* __restrict__ dst,
                                                  int* __restrict__ cnt,
                                                  int* __restrict__ bucket) {
  const int tid = threadIdx.x;

  if (blockIdx.x >= GB1) {   // ---- bucket build ----
    int e = (blockIdx.x - GB1) * 256 + tid;
    if (e < N_EDGES) {
      int s = src[e];
      int d = dst[e];
      int slot = atomicAdd(&cnt[d], 1);
      if (slot < CAP) bucket[d * CAP + slot] = s << 6;   // s * HID
    }
    return;
  }

  // ---- GEMM: 128-row tile ----
  __shared__ ushort xs[128][64];   // [row][k], 16B chunks XOR-swizzled by row&7
  __shared__ ushort ws[64][64];    // [col][k]
  const int row0 = blockIdx.x * 128;
  const int wave = tid >> 6, lane = tid & 63, quad = lane >> 4, l16 = lane & 15;

  // X staging: 2 threads/row, 32 k-cols each
  const int srow = tid >> 1;
  const int sk   = (tid & 1) * 32;
  int gr = row0 + srow;
  gr = gr < N_NODES ? gr : N_NODES - 1;
  const float* xrow = &X[(size_t)gr * IN_DIM + sk];
  // WT staging: 4 threads/col, TWO 16B chunks each (8 chunks per 64-elem row)
  const int wrow = tid >> 2;
  const int wc0  = (tid & 3) * 2;
  const ushort* wrp = &WT[(size_t)wrow * IN_DIM + wc0 * 8];

  f32x4 acc[2][4] = {};

  float4 xv[8];
#pragma unroll
  for (int i = 0; i < 8; i++) xv[i] = *(const float4*)&xrow[i * 4];
  uint4 wv0 = *(const uint4*)&wrp[0];
  uint4 wv1 = *(const uint4*)&wrp[8];

  for (int kt = 0; kt < IN_DIM; kt += 64) {
    unsigned int xw[16];
#pragma unroll
    for (int i = 0; i < 8; i++) {
      xw[i * 2 + 0] = f2bf2(xv[i].x, xv[i].y);
      xw[i * 2 + 1] = f2bf2(xv[i].z, xv[i].w);
    }
#pragma unroll
    for (int j = 0; j < 4; j++)
      *(uint4*)&xs[srow][(((sk >> 3) + j) ^ (srow & 7)) * 8] = *(const uint4*)&xw[j * 4];
    *(uint4*)&ws[wrow][((wc0 + 0) ^ (wrow & 7)) * 8] = wv0;
    *(uint4*)&ws[wrow][((wc0 + 1) ^ (wrow & 7)) * 8] = wv1;

    // prefetch next tile BEFORE the barrier: loads stay in flight across it
    if (kt + 64 < IN_DIM) {
#pragma unroll
      for (int i = 0; i < 8; i++) xv[i] = *(const float4*)&xrow[kt + 64 + i * 4];
      wv0 = *(const uint4*)&wrp[kt + 64];
      wv1 = *(const uint4*)&wrp[kt + 64 + 8];
    }
    __syncthreads();

    const int ar0 = wave * 32 + l16;
    const int ar1 = ar0 + 16;
#pragma unroll
    for (int ks = 0; ks < 2; ks++) {
      bf16x8 a0 = *(const bf16x8*)&xs[ar0][((ks * 4 + quad) ^ (ar0 & 7)) * 8];
      bf16x8 a1 = *(const bf16x8*)&xs[ar1][((ks * 4 + quad) ^ (ar1 & 7)) * 8];
#pragma unroll
      for (int ct = 0; ct < 4; ct++) {
        const int br = ct * 16 + l16;
        bf16x8 b = *(const bf16x8*)&ws[br][((ks * 4 + quad) ^ (br & 7)) * 8];
        acc[0][ct] = __builtin_amdgcn_mfma_f32_16x16x32_bf16(a0, b, acc[0][ct], 0, 0, 0);
        acc[1][ct] = __builtin_amdgcn_mfma_f32_16x16x32_bf16(a1, b, acc[1][ct], 0, 0, 0);
      }
    }
    __syncthreads();
  }

#pragma unroll
  for (int g2 = 0; g2 < 2; g2++)
#pragma unroll
    for (int ct = 0; ct < 4; ct++)
#pragma unroll
      for (int r = 0; r < 4; r++) {
        int row = row0 + wave * 32 + g2 * 16 + quad * 4 + r;
        if (row < N_NODES)
          P[(size_t)row * HID + ct * 16 + l16] = f2bf1(acc[g2][ct][r]);
      }
}

// Fused GIN layer, 512 threads / 8 waves per 64-node tile.
// Gather uses 8 threads/node (one uint4 per neighbor per thread) -> 2x the
// independent latency chains of the 4-thread version. MFMA GEMM1 + pool on
// waves 0-3; CHAIN's GEMM2 runs on waves 4-7 concurrently with the pool.
template <int CHAIN>
__global__ __launch_bounds__(512) void fused_mlp(
    const int* __restrict__ cnt, const int* __restrict__ bucket,
    const ushort* __restrict__ Pin,
    const float* __restrict__ bin, const float* __restrict__ g,
    const float* __restrict__ be, const float* __restrict__ rm,
    const float* __restrict__ rv,
    const ushort* __restrict__ WT1, const float* __restrict__ b1,
    const ushort* __restrict__ WT2, ushort* __restrict__ OUT2,
    const int* __restrict__ batch, const float* __restrict__ wlh,
    float* __restrict__ out) {
  __shared__ ushort xs[64][64];             // swizzled A-tile
  __shared__ ushort ws[64][64];             // WT1 [col][k] swizzled
  __shared__ ushort ws2[CHAIN ? 64 : 1][64];// WT2 (CHAIN only)
  __shared__ float sS[64], sT[64];
  __shared__ float gacc[64];                // 32-graph pooling window
  __shared__ float wl_s[2 * HID];           // this layer's half of wl: [64][2]
  __shared__ int   sbatch[64];              // batch ids of this tile (sorted)
  const int tid  = threadIdx.x;
  const int row0 = blockIdx.x * 64;
  const int srow = tid >> 3;        // node-in-tile (staging), 0..63
  const int sub8 = tid & 7;         // 8-col group
  const int col0 = sub8 * 8;

  // ---- early issue: heads of the gather dependency chain ----
  int node = row0 + srow;
  node = node < N_NODES ? node : N_NODES - 1;
  const int c_raw = cnt[node];
  const int* bkt = &bucket[node * CAP];
  const int4 pre = *(const int4*)bkt;     // safe read; values used only if c>=4
  const uint4 swv = *(const uint4*)&Pin[node * HID + col0];

  if (tid < 64) {
    int nb = row0 + tid;
    sbatch[tid] = batch[nb < N_NODES ? nb : N_NODES - 1];
    gacc[tid] = 0.0f;
    float s = g[tid] * rsqrtf(rv[tid] + BN_EPS);
    sS[tid] = s;
    sT[tid] = (bin[tid] - rm[tid]) * s + be[tid];
  }
  if (tid < 2 * HID) wl_s[tid] = wlh[tid];
  {
    // weight staging: 512 threads = 64 rows x 8 chunks, one uint4 each
    uint4 w0 = *(const uint4*)&WT1[(size_t)srow * HID + col0];
    *(uint4*)&ws[srow][(sub8 ^ (srow & 7)) * 8] = w0;
    if (CHAIN) {
      uint4 v0 = *(const uint4*)&WT2[(size_t)srow * HID + col0];
      *(uint4*)&ws2[srow][(sub8 ^ (srow & 7)) * 8] = v0;
    }
  }
  __syncthreads();   // sS/sT/sbatch/gacc/wl_s/ws/ws2 ready

  // ---- gather + BN + ReLU -> stage h into xs (8 threads/node) ----
  {
    unsigned int sw[4];
    *(uint4*)&sw[0] = swv;
    f32x2 acc2[4];
#pragma unroll
    for (int j = 0; j < 4; j++) acc2[j] = unpk(sw[j]);

    int c = c_raw < CAP ? c_raw : CAP;
    int i = 0;
    if (c >= 4) {
      int4 s4 = pre;
      for (; i + 4 <= c; i += 4) {
        const int4 cur = s4;
        if (i + 8 <= c) s4 = *(const int4*)&bkt[i + 4];   // prefetch next chunk
        unsigned int w0[4], w1[4], w2[4], w3[4];
        *(uint4*)&w0[0] = *(const uint4*)&Pin[cur.x + col0];  // premult offsets
        *(uint4*)&w1[0] = *(const uint4*)&Pin[cur.y + col0];
        *(uint4*)&w2[0] = *(const uint4*)&Pin[cur.z + col0];
        *(uint4*)&w3[0] = *(const uint4*)&Pin[cur.w + col0];
#pragma unroll
        for (int j = 0; j < 4; j++)
          acc2[j] += (unpk(w0[j]) + unpk(w1[j])) + (unpk(w2[j]) + unpk(w3[j]));
      }
    }
    for (; i < c; i++) {
      unsigned int w0[4];
      *(uint4*)&w0[0] = *(const uint4*)&Pin[bkt[i] + col0];
#pragma unroll
      for (int j = 0; j < 4; j++) acc2[j] += unpk(w0[j]);
    }

    unsigned int hw[4];
#pragma unroll
    for (int j = 0; j < 4; j++) {
      const int col = col0 + j * 2;
      float x0 = fmaxf(fmaf(acc2[j].x, sS[col],     sT[col]),     0.0f);
      float x1 = fmaxf(fmaf(acc2[j].y, sS[col + 1], sT[col + 1]), 0.0f);
      hw[j] = f2bf2(x0, x1);
    }
    *(uint4*)&xs[srow][(sub8 ^ (srow & 7)) * 8] = *(const uint4*)&hw[0];
  }
  __syncthreads();   // xs ready

  const int wave = tid >> 6, lane = tid & 63, quad = lane >> 4, l16 = lane & 15;
  const int g0 = sbatch[0], g1v = sbatch[63];
  const bool small = (g1v - g0) < 32;

  float v[4][4];
  if (wave < 4) {
    // ---- GEMM 1: h @ W1 (waves 0-3; wave-local A rows) ----
    const int ar = wave * 16 + l16, axor = ar & 7;
    f32x4 acc1[4] = {};
#pragma unroll
    for (int ks = 0; ks < 2; ks++) {
      bf16x8 a = *(const bf16x8*)&xs[ar][((ks * 4 + quad) ^ axor) * 8];
#pragma unroll
      for (int ct = 0; ct < 4; ct++) {
        const int br = ct * 16 + l16;
        bf16x8 b = *(const bf16x8*)&ws[br][((ks * 4 + quad) ^ (br & 7)) * 8];
        acc1[ct] = __builtin_amdgcn_mfma_f32_16x16x32_bf16(a, b, acc1[ct], 0, 0, 0);
      }
    }
    // epilogue: xL = relu(acc1 + b1) (C layout: col=ct*16+l16, row=quad*4+r)
#pragma unroll
    for (int ct = 0; ct < 4; ct++) {
      const float bo = b1[ct * 16 + l16];
#pragma unroll
      for (int r = 0; r < 4; r++) v[ct][r] = fmaxf(acc1[ct][r] + bo, 0.0f);
    }
    if (CHAIN) {
      // restage bf16(xL) into xs (wave-local rows; reads completed via dep on v)
#pragma unroll
      for (int ct = 0; ct < 4; ct++) {
        const int col = ct * 16 + l16;
#pragma unroll
        for (int r = 0; r < 4; r++) {
          int lrow = wave * 16 + quad * 4 + r;
          xs[lrow][(((col >> 3) ^ (lrow & 7)) * 8) + (col & 7)] = f2bf1(v[ct][r]);
        }
      }
    }
  }

  if (CHAIN) {
    __syncthreads();   // restaged xs visible to waves 4-7
    if (wave >= 4) {
      // ---- GEMM 2: xL @ W2 -> OUT2 (waves 4-7, overlaps waves 0-3's pool) ----
      const int wv = wave - 4;
      const int ar = wv * 16 + l16, axor = ar & 7;
      f32x4 accB[4] = {};
#pragma unroll
      for (int ks = 0; ks < 2; ks++) {
        bf16x8 a = *(const bf16x8*)&xs[ar][((ks * 4 + quad) ^ axor) * 8];
#pragma unroll
        for (int ct = 0; ct < 4; ct++) {
          const int br = ct * 16 + l16;
          bf16x8 b = *(const bf16x8*)&ws2[br][((ks * 4 + quad) ^ (br & 7)) * 8];
          accB[ct] = __builtin_amdgcn_mfma_f32_16x16x32_bf16(a, b, accB[ct], 0, 0, 0);
        }
      }
#pragma unroll
      for (int ct = 0; ct < 4; ct++) {
        const int col = ct * 16 + l16;
#pragma unroll
        for (int r = 0; r < 4; r++) {
          int grow = row0 + wv * 16 + quad * 4 + r;
          if (grow < N_NODES) OUT2[(size_t)grow * HID + col] = f2bf1(accB[ct][r]);
        }
      }
    }
  }

  if (wave < 4) {
    // ---- fused pool partial: p[r] = xL[row] . wlh ----
    float p0[4] = {}, p1[4] = {};
#pragma unroll
    for (int ct = 0; ct < 4; ct++) {
      const int col = ct * 16 + l16;
      const float w0 = wl_s[col * 2 + 0], w1 = wl_s[col * 2 + 1];
#pragma unroll
      for (int r = 0; r < 4; r++) {
        p0[r] = fmaf(v[ct][r], w0, p0[r]);
        p1[r] = fmaf(v[ct][r], w1, p1[r]);
      }
    }
#pragma unroll
    for (int m = 1; m < 16; m <<= 1) {
#pragma unroll
      for (int r = 0; r < 4; r++) {
        p0[r] += __shfl_xor(p0[r], m);
        p1[r] += __shfl_xor(p1[r], m);
      }
    }
    if (l16 == 0) {
#pragma unroll
      for (int r = 0; r < 4; r++) {
        int lrow = wave * 16 + quad * 4 + r;
        if (row0 + lrow < N_NODES) {
          int gi = sbatch[lrow];
          if (small) {
            atomicAdd(&gacc[(gi - g0) * 2 + 0], p0[r]);
            atomicAdd(&gacc[(gi - g0) * 2 + 1], p1[r]);
          } else {
            atomicAdd(&out[gi * 2 + 0], p0[r]);
            atomicAdd(&out[gi * 2 + 1], p1[r]);
          }
        }
      }
    }
  }

  // ---- flush per-block graph partials (tiny window: batch is sorted) ----
  __syncthreads();
  if (small) {
    const int span2 = (g1v - g0 + 1) * 2;
    for (int z = tid; z < span2; z += 512) {
      float vv = gacc[z];
      if (vv != 0.0f) atomicAdd(&out[g0 * 2 + z], vv);
    }
  }
}

extern "C" void kernel_launch(void* const* d_in, const int* in_sizes, int n_in,
                              void* d_out, int out_size, void* d_ws, size_t ws_size,
                              hipStream_t stream) {
  const float* x   = (const float*)d_in[0];
  const int*   ei  = (const int*)d_in[1];
  const int*   bat = (const int*)d_in[2];
  const float* w1a = (const float*)d_in[3];
  const float* b1a = (const float*)d_in[4];
  const float* g1  = (const float*)d_in[5];
  const float* be1 = (const float*)d_in[6];
  const float* rm1 = (const float*)d_in[7];
  const float* rv1 = (const float*)d_in[8];
  const float* w1b = (const float*)d_in[9];
  const float* b1b = (const float*)d_in[10];
  const float* w2a = (const float*)d_in[11];
  const float* b2a = (const float*)d_in[12];
  const float* g2  = (const float*)d_in[13];
  const float* be2 = (const float*)d_in[14];
  const float* rm2 = (const float*)d_in[15];
  const float* rv2 = (const float*)d_in[16];
  const float* w2b = (const float*)d_in[17];
  const float* b2b = (const float*)d_in[18];
  const float* wl  = (const float*)d_in[19];
  const float* bl  = (const float*)d_in[20];
  float* out = (float*)d_out;

  const int* src = ei;
  const int* dst = ei + N_EDGES;

  const size_t FB = (size_t)N_NODES * HID;
  ushort* P1   = (ushort*)d_ws;              // 6.4 MB
  ushort* P2   = P1 + FB;                    // 6.4 MB
  ushort* WT   = P2 + FB;                    // 96 KB (w1a^T)
  ushort* WT1b = WT + (size_t)W1A_E;         // 8 KB each
  ushort* WT2a = WT1b + WB_E;
  ushort* WT2b = WT2a + WB_E;
  int* cnt     = (int*)(WT2b + WB_E);        // 200 KB
  int* bucket  = cnt + N_NODES;              // 12.8 MB  (total ~26 MB)

  const int CB = (W1A_E + 3 * WB_E + N_GRAPHS * 2 + N_NODES + 255) / 256;

  // weights->bf16^T, out=bl, cnt=0
  convert_all<<<CB, 256, 0, stream>>>(w1a, w1b, w2a, w2b, bl,
                                      WT, WT1b, WT2a, WT2b, out, cnt);
  // Hybrid: P1 = x @ w1a (MFMA) + bucket build (overlapped, independent)
  gemm_build<<<GB1 + BB, 256, 0, stream>>>(x, WT, P1, src, dst, cnt, bucket);
  // Layer 1: gather(P1)+BN+ReLU, @w1b+b1b+ReLU = x1; pool x1.wl[0:64];
  //          chain P2 = x1 @ w2a (waves 4-7)
  fused_mlp<1><<<GBF, 512, 0, stream>>>(cnt, bucket, P1, b1a, g1, be1, rm1, rv1,
                                        WT1b, b1b, WT2a, P2, bat, wl, out);
  // Layer 2: gather(P2)+BN+ReLU, @w2b+b2b+ReLU = x2; pool x2.wl[64:128]
  fused_mlp<0><<<GBF, 512, 0, stream>>>(cnt, bucket, P2, b2a, g2, be2, rm2, rv2,
                                        WT2b, b2b, nullptr, nullptr, bat,
                                        wl + 2 * HID, out);
}